// Round 4
// baseline (81.482 us; speedup 1.0000x reference)
//
#include <hip/hip_runtime.h>

// S4D kernel: K[h,l] = 2 * Re( sum_n Ct[h,n] * z[h,n]^l )
//   z  = exp(dtA),  dtA = (-exp(log_A_real) + i*A_imag) * exp(log_dt[h])
//   Ct = (C_real + i*C_imag) * (z - 1) / A
//
// R4 structure (one 256-thread block per h; thread t owns l = t + 256*j):
//  - real 2nd-order recurrence x_{j+1} = 2Re(w) x_j - |w|^2 x_{j-1}, w=z^256,
//    two n's packed per v2f lane. PING-PONG unroll (j by 2): x/xm swap roles,
//    exactly 3 pk ops per (pair, j) step, no register copies.
//  - adaptive j-cutoff: |w| = exp(256*Re(dtA)) < 1; drop j-tail when
//    2*sum|Ct| * rmax^j / (1-rmax) < 1e-3 (abs threshold is 3.9e-2 -> 13x
//    margin over total error). Block-uniform (dt per h) -> scalar branch.
//  - per-thread skip: high-t threads in high-dt blocks have |z|^t tiny;
//    whole contribution bounded < 1e-3 -> skip setup+main, store zeros.
//  - runtime-detected uniform Re(dtA) across n (true for this data:
//    log_A_real == log 0.5) -> hoist exp2(dR*l2e*t): 1 trans/thread not 32.
//  - per-n setup constants packed as two float4 LDS arrays (2x ds_read_b128).

#define N2    32
#define NPAIR (N2 / 2)
#define LLEN  4096
#define BLK   256
#define CL    (LLEN / BLK)  // 16 outputs per thread
#define PCH   4             // pairs per chunk (8 n's)
#define TOL   1e-3f

typedef float v2f __attribute__((ext_vector_type(2)));

__global__ __launch_bounds__(BLK, 4) void s4d_kernel(
    const float* __restrict__ log_dt,
    const float* __restrict__ C_real,
    const float* __restrict__ C_imag,
    const float* __restrict__ log_A_real,
    const float* __restrict__ A_imag,
    float* __restrict__ out)
{
    const int h = blockIdx.x;
    const int t = threadIdx.x;

    __shared__ float4 sP[N2];      // {th, tl, dR*log2e, 1/|w|^2}
    __shared__ float4 sQ[N2];      // {Ctr, Cti, Re(w), Im(w)}
    __shared__ v2f    s2A[NPAIR];  // 2*Re(w) per n, packed by pair
    __shared__ v2f    sMR2[NPAIR]; // -|w|^2 per n, packed by pair
    __shared__ float  sUdr, sSA, sRmax;
    __shared__ int    sJcut, sFlag;

    // ---- per-(h,n) setup: lanes 0..31 (all in wave 0) ----
    if (t < N2) {
        const int n = t;
        const float dt = __expf(log_dt[h]);
        const float aR = -__expf(log_A_real[h * N2 + n]);
        const float aI = A_imag[h * N2 + n];
        const float dR = aR * dt;

        // step phase in revolutions, double -> (hi, lo) split
        const double trev = (double)aI * (double)dt * 0.15915494309189535;
        const float  th   = (float)trev;
        const float  tl   = (float)(trev - (double)th);

        // z = exp(dtA)
        double pz = trev; pz -= floor(pz);
        const float e1 = __expf(dR);
        const float zr = e1 * __builtin_amdgcn_cosf((float)pz);
        const float zi = e1 * __builtin_amdgcn_sinf((float)pz);

        // q = (z - 1) / A ; Ct = C * q
        const float inv = 1.0f / (aR * aR + aI * aI);
        const float nr  = zr - 1.0f;
        const float qr  = (nr * aR + zi * aI) * inv;
        const float qi  = (zi * aR - nr * aI) * inv;
        const float c_r = C_real[h * N2 + n], c_i = C_imag[h * N2 + n];
        const float Ctr = c_r * qr - c_i * qi;
        const float Cti = c_r * qi + c_i * qr;

        // w = z^256
        double p256 = trev * 256.0; p256 -= floor(p256);
        const float ew = __expf(dR * 256.0f);
        const float wx = ew * __builtin_amdgcn_cosf((float)p256);
        const float wy = ew * __builtin_amdgcn_sinf((float)p256);
        const float r2 = ew * ew;
        const float drl2 = dR * 1.4426950408889634f;

        sP[n] = make_float4(th, tl, drl2, 1.0f / r2);
        sQ[n] = make_float4(Ctr, Cti, wx, wy);
        ((float*)s2A)[n]  = 2.0f * wx;
        ((float*)sMR2)[n] = -r2;

        // block-level bounds: S = sum_n (|Ctr|+|Cti|) >= sum|Ct|, rmax = max|w|
        float S = fabsf(Ctr) + fabsf(Cti);
        float r = ew;
#pragma unroll
        for (int m = 16; m >= 1; m >>= 1) {
            S += __shfl_xor(S, m, 32);
            r  = fmaxf(r, __shfl_xor(r, m, 32));
        }
        const float u = __shfl(drl2, 0, 32);
        const unsigned long long bal = __ballot(drl2 == u);
        if (n == 0) {
            sFlag = ((bal & 0xFFFFFFFFull) == 0xFFFFFFFFull) ? 1 : 0;
            sUdr  = u;
            sSA   = S;
            sRmax = r;
            int jc = CL;
            if (r < 0.9999f) {          // r>=1 (dR>=0) -> no decay, keep all j
                const float tail0 = 2.0f * S / (1.0f - r);
                jc = 0;
                float rj = 1.0f;
                while (jc < CL && tail0 * rj >= TOL) { rj *= r; ++jc; }
            }
            sJcut = jc;
        }
    }
    __syncthreads();

    v2f acc[CL];
#pragma unroll
    for (int j = 0; j < CL; ++j) acc[j] = (v2f){0.0f, 0.0f};

    const float tf    = (float)t;
    const int   jcut  = __builtin_amdgcn_readfirstlane(sJcut);
    const int   flagU = __builtin_amdgcn_readfirstlane(sFlag);

    bool  active = (jcut > 0);
    float erU    = 1.0f;
    if (flagU) {
        erU = __builtin_amdgcn_exp2f(sUdr * tf);
        // everything this thread contributes is bounded by 2*S*|z|^t/(1-rmax)
        if (sRmax < 0.9999f && 2.0f * sSA * erU / (1.0f - sRmax) < TOL)
            active = false;
    }

    if (active) {
        for (int p0 = 0; p0 < NPAIR; p0 += PCH) {
            v2f x[PCH], xm[PCH], c2a[PCH], cmr[PCH];

#pragma unroll
            for (int k = 0; k < PCH; ++k) {
                const int pair = p0 + k;
                c2a[k] = s2A[pair];
                cmr[k] = sMR2[pair];
#pragma unroll
                for (int e = 0; e < 2; ++e) {
                    const int n = 2 * pair + e;
                    const float4 P = sP[n];          // ds_read_b128
                    const float4 Q = sQ[n];          // ds_read_b128
                    const float er = flagU ? erU
                                           : __builtin_amdgcn_exp2f(P.z * tf);
                    // phase(t) = fract(t * (th+tl)), compensated in fp32
                    const float p    = P.x * tf;
                    const float perr = __builtin_fmaf(P.x, tf, -p);
                    const float f    = __builtin_amdgcn_fractf(p)
                                     + __builtin_fmaf(P.y, tf, perr);
                    const float c = __builtin_amdgcn_cosf(f);
                    const float s = __builtin_amdgcn_sinf(f);
                    const float x0  = er * __builtin_fmaf(-Q.y, s, Q.x * c);
                    const float y0  = er * __builtin_fmaf( Q.y, c, Q.x * s);
                    const float xm1 = __builtin_fmaf(y0, Q.w, x0 * Q.z) * P.w;
                    if (e == 0) { x[k].x = x0; xm[k].x = xm1; }
                    else        { x[k].y = x0; xm[k].y = xm1; }
                }
            }

            // ping-pong 2nd-order recurrence: 3 pk ops per step, no copies
#pragma unroll
            for (int jp = 0; jp < CL / 2; ++jp) {
                if (2 * jp < jcut) {
#pragma unroll
                    for (int k = 0; k < PCH; ++k) {
                        acc[2 * jp] += x[k];
                        xm[k] = c2a[k] * x[k] + cmr[k] * xm[k];  // -> x_{j+1}
                    }
#pragma unroll
                    for (int k = 0; k < PCH; ++k) {
                        acc[2 * jp + 1] += xm[k];
                        x[k] = c2a[k] * xm[k] + cmr[k] * x[k];   // -> x_{j+2}
                    }
                }
            }
        }
    }

    float* __restrict__ o = out + (size_t)h * LLEN + t;
#pragma unroll
    for (int j = 0; j < CL; ++j) o[j * BLK] = 2.0f * (acc[j].x + acc[j].y);
}

extern "C" void kernel_launch(void* const* d_in, const int* in_sizes, int n_in,
                              void* d_out, int out_size, void* d_ws, size_t ws_size,
                              hipStream_t stream) {
    const float* log_dt     = (const float*)d_in[0];
    const float* C_real     = (const float*)d_in[1];
    const float* C_imag     = (const float*)d_in[2];
    const float* log_A_real = (const float*)d_in[3];
    const float* A_imag     = (const float*)d_in[4];
    float* out = (float*)d_out;

    const int H = in_sizes[0];  // 1024; one block per h
    s4d_kernel<<<dim3(H), dim3(BLK), 0, stream>>>(
        log_dt, C_real, C_imag, log_A_real, A_imag, out);
}

// Round 5
// 78.136 us; speedup vs baseline: 1.0428x; 1.0428x over previous
//
#include <hip/hip_runtime.h>

// S4D kernel: K[h,l] = 2 * Re( sum_n Ct[h,n] * z[h,n]^l )
//   z  = exp(dtA),  dtA = (-exp(log_A_real) + i*A_imag) * exp(log_dt[h])
//   Ct = (C_real + i*C_imag) * (z - 1) / A
//
// R5 structure (one 256-thread block per h; thread t owns l = t + 256*j):
//  - LDS FACTOR TABLES kill all per-(t,n) transcendentals (was 64/thread):
//      T0[n][k]  = z^k                      (k = t & 15)
//      U1[n][m]  = {Ct z^(16m), Ct z^(16m+256)}   (m = t >> 4)
//    start states: x0 = Re(U1.lo * T0) ; x1 = Re(U1.hi * T0)
//    -> 4 fma + 1 b64 + 1 b128 LDS read per (t,n). No trans, no fp64,
//       no 1/|w|^2 correction (x1 comes from the +256 table half).
//  - real 2nd-order recurrence x_{j+1} = 2Re(w) x_j - |w|^2 x_{j-1},
//    w = z^256, two n's packed per v2f, ping-pong (3 pk ops/step, no copies).
//  - block-uniform adaptive j-cutoff + per-thread decay skip (bounds use
//    TOL=1e-3 vs 3.9e-2 threshold).

#define N2    32
#define NPAIR (N2 / 2)
#define LLEN  4096
#define BLK   256
#define CL    (LLEN / BLK)  // 16 outputs per thread
#define PCH   4             // pairs per chunk (8 n's)
#define TOL   1e-3f

typedef float v2f __attribute__((ext_vector_type(2)));

__global__ __launch_bounds__(BLK, 4) void s4d_kernel(
    const float* __restrict__ log_dt,
    const float* __restrict__ C_real,
    const float* __restrict__ C_imag,
    const float* __restrict__ log_A_real,
    const float* __restrict__ A_imag,
    float* __restrict__ out)
{
    const int h = blockIdx.x;
    const int t = threadIdx.x;

    __shared__ v2f    sT0[N2][16];   // z^k
    __shared__ float4 sU1[N2][16];   // {Re,Im of Ct z^(16m), Re,Im of Ct z^(16m+256)}
    __shared__ v2f    s2A[NPAIR];    // 2*Re(w), packed by n-pair
    __shared__ v2f    sMR2[NPAIR];   // -|w|^2, packed by n-pair
    __shared__ v2f    sCt[N2];
    __shared__ float  sDrl2[N2];     // Re(dtA) * log2(e)
    __shared__ double sTrev[N2];     // step phase in revolutions (double)
    __shared__ float  sS, sRmax, sDrmax;
    __shared__ int    sJcut;

    // ---- stage A: per-(h,n) params, lanes 0..31 (wave 0, cold) ----
    if (t < N2) {
        const int n = t;
        const float dt = __expf(log_dt[h]);
        const float aR = -__expf(log_A_real[h * N2 + n]);
        const float aI = A_imag[h * N2 + n];
        const float dR = aR * dt;

        const double trev = (double)aI * (double)dt * 0.15915494309189535;

        // z = exp(dtA)
        double pz = trev; pz -= floor(pz);
        const float e1 = __expf(dR);
        const float zr = e1 * __builtin_amdgcn_cosf((float)pz);
        const float zi = e1 * __builtin_amdgcn_sinf((float)pz);

        // q = (z - 1)/A ; Ct = C * q
        const float inv = 1.0f / (aR * aR + aI * aI);
        const float nr  = zr - 1.0f;
        const float qr  = (nr * aR + zi * aI) * inv;
        const float qi  = (zi * aR - nr * aI) * inv;
        const float c_r = C_real[h * N2 + n], c_i = C_imag[h * N2 + n];
        const float Ctr = c_r * qr - c_i * qi;
        const float Cti = c_r * qi + c_i * qr;

        // w = z^256
        double p256 = trev * 256.0; p256 -= floor(p256);
        const float ew = __expf(dR * 256.0f);
        const float wx = ew * __builtin_amdgcn_cosf((float)p256);
        const float r2 = ew * ew;
        const float drl2 = dR * 1.4426950408889634f;

        sCt[n]   = (v2f){Ctr, Cti};
        sDrl2[n] = drl2;
        sTrev[n] = trev;
        ((float*)s2A)[n]  = 2.0f * wx;
        ((float*)sMR2)[n] = -r2;

        // block bounds: S >= sum|Ct|, rmax = max|w|, drmax = max drl2
        float S = fabsf(Ctr) + fabsf(Cti);
        float r = ew;
        float dm = drl2;
#pragma unroll
        for (int m = 16; m >= 1; m >>= 1) {
            S  += __shfl_xor(S, m, 32);
            r   = fmaxf(r,  __shfl_xor(r,  m, 32));
            dm  = fmaxf(dm, __shfl_xor(dm, m, 32));
        }
        if (n == 0) {
            sS = S; sRmax = r; sDrmax = dm;
            int jc = CL;
            if (r < 0.9999f) {
                const float tail0 = 2.0f * S / (1.0f - r);
                jc = 0;
                float rj = 1.0f;
                while (jc < CL && tail0 * rj >= TOL) { rj *= r; ++jc; }
            }
            sJcut = jc;
        }
    }
    __syncthreads();

    // ---- stage B: build factor tables (1024 tasks / 256 threads) ----
#pragma unroll
    for (int it = 0; it < 4; ++it) {
        const int tau = t + BLK * it;
        if (tau < 512) {                      // T0 tasks (it = 0,1: uniform)
            const int n = tau >> 4, k = tau & 15;
            double p = sTrev[n] * (double)k; p -= floor(p);
            const float g = __builtin_amdgcn_exp2f(sDrl2[n] * (float)k);
            sT0[n][k] = (v2f){ g * __builtin_amdgcn_cosf((float)p),
                               g * __builtin_amdgcn_sinf((float)p) };
        } else {                              // U1 tasks (it = 2,3: uniform)
            const int tu = tau - 512;
            const int n = tu >> 4, m = tu & 15;
            const v2f    Ct = sCt[n];
            const double tr = sTrev[n];
            const float  dl = sDrl2[n];

            double p0 = tr * (double)(16 * m); p0 -= floor(p0);
            const float g0 = __builtin_amdgcn_exp2f(dl * (float)(16 * m));
            const float c0 = g0 * __builtin_amdgcn_cosf((float)p0);
            const float s0 = g0 * __builtin_amdgcn_sinf((float)p0);

            double p1 = tr * (double)(16 * m + 256); p1 -= floor(p1);
            const float g1 = __builtin_amdgcn_exp2f(dl * (float)(16 * m + 256));
            const float c1 = g1 * __builtin_amdgcn_cosf((float)p1);
            const float s1 = g1 * __builtin_amdgcn_sinf((float)p1);

            sU1[n][m] = make_float4(Ct.x * c0 - Ct.y * s0,
                                    Ct.x * s0 + Ct.y * c0,
                                    Ct.x * c1 - Ct.y * s1,
                                    Ct.x * s1 + Ct.y * c1);
        }
    }
    __syncthreads();

    v2f acc[CL];
#pragma unroll
    for (int j = 0; j < CL; ++j) acc[j] = (v2f){0.0f, 0.0f};

    const int jcut = __builtin_amdgcn_readfirstlane(sJcut);
    bool active = (jcut > 0);
    {
        const float rmax = sRmax;
        if (rmax < 0.9999f) {
            const float bound = 2.0f * sS *
                __builtin_amdgcn_exp2f(sDrmax * (float)t) / (1.0f - rmax);
            if (bound < TOL) active = false;
        }
    }

    if (active) {
        const int t0 = t & 15, t1 = t >> 4;

        for (int p0 = 0; p0 < NPAIR; p0 += PCH) {
            v2f xa[PCH], xb[PCH], c2a[PCH], cmr[PCH];   // xa=x0, xb=x1

#pragma unroll
            for (int k = 0; k < PCH; ++k) {
                const int pair = p0 + k;
                c2a[k] = s2A[pair];
                cmr[k] = sMR2[pair];
#pragma unroll
                for (int e = 0; e < 2; ++e) {
                    const int n = 2 * pair + e;
                    const v2f    b = sT0[n][t0];       // ds_read_b64
                    const float4 u = sU1[n][t1];       // ds_read_b128
                    const float x0 = __builtin_fmaf(-u.y, b.y, u.x * b.x);
                    const float x1 = __builtin_fmaf(-u.w, b.y, u.z * b.x);
                    if (e == 0) { xa[k].x = x0; xb[k].x = x1; }
                    else        { xa[k].y = x0; xb[k].y = x1; }
                }
            }

            // j = 0, 1
#pragma unroll
            for (int k = 0; k < PCH; ++k) acc[0] += xa[k];
            if (jcut > 1) {
#pragma unroll
                for (int k = 0; k < PCH; ++k) acc[1] += xb[k];
            }

            // j = 2..15: ping-pong, 3 pk ops per (pair, j), no copies
#pragma unroll
            for (int jp = 0; jp < (CL - 2) / 2; ++jp) {
                const int j = 2 + 2 * jp;
                if (j < jcut) {
#pragma unroll
                    for (int k = 0; k < PCH; ++k) {
                        xa[k] = c2a[k] * xb[k] + cmr[k] * xa[k];  // x_{j}
                        acc[j] += xa[k];
                    }
#pragma unroll
                    for (int k = 0; k < PCH; ++k) {
                        xb[k] = c2a[k] * xa[k] + cmr[k] * xb[k];  // x_{j+1}
                        acc[j + 1] += xb[k];
                    }
                }
            }
        }
    }

    float* __restrict__ o = out + (size_t)h * LLEN + t;
#pragma unroll
    for (int j = 0; j < CL; ++j) o[j * BLK] = 2.0f * (acc[j].x + acc[j].y);
}

extern "C" void kernel_launch(void* const* d_in, const int* in_sizes, int n_in,
                              void* d_out, int out_size, void* d_ws, size_t ws_size,
                              hipStream_t stream) {
    const float* log_dt     = (const float*)d_in[0];
    const float* C_real     = (const float*)d_in[1];
    const float* C_imag     = (const float*)d_in[2];
    const float* log_A_real = (const float*)d_in[3];
    const float* A_imag     = (const float*)d_in[4];
    float* out = (float*)d_out;

    const int H = in_sizes[0];  // 1024; one block per h
    s4d_kernel<<<dim3(H), dim3(BLK), 0, stream>>>(
        log_dt, C_real, C_imag, log_A_real, A_imag, out);
}